// Round 12
// baseline (3641.694 us; speedup 1.0000x reference)
//
#include <hip/hip_runtime.h>
#include <math.h>

#define BB 16
#define CC 128
#define LL 16000
#define KK 256
#define SS 3937
#define MM 4000
#define THRS 0.5f
#define STEP 0.1f   // float32(0.01/0.1) == 0.1f

typedef int v16i __attribute__((ext_vector_type(16)));

// ---------------------------------------------------------------------------
// Strided conv1d (K=256, stride=4), fp32 register-tiled implicit GEMM.
// Accumulation: single fmaf chain per output, k strictly ascending 0..255.
// [bit-path: DO NOT change arithmetic order]
// R12 layout: tx indexes s (coalesced epilogue: 64B runs), ty indexes c.
// W staged in natural [c][k] rows (stride 68 floats: 16B-aligned, 2-way-free
// banks) -> w reads are 8 broadcast b128/kk4 instead of 32 b32. Double-
// buffered chunks; whole-window zero-skip for MODE 1.
// ---------------------------------------------------------------------------
template<int MODE>
__global__ __launch_bounds__(256, 2) void k_conv(
    const float* __restrict__ in0,     // x (MODE 0) or recon (MODE 1), [B][LL]
    const float* __restrict__ W,       // [C][K] natural
    float* __restrict__ drive,
    float* __restrict__ u)
{
    __shared__ __align__(16) float sW[2][128 * 68];  // 2 x 34.8 KB
    __shared__ __align__(16) float sX[768];          // full x window
    __shared__ int sFlag;

    const int tid = threadIdx.x;
    const int tx = tid & 15;          // s-minor
    const int ty = tid >> 4;          // c-minor
    const int s0 = blockIdx.x * 128;
    const int b  = blockIdx.y;

    const int sc = tid >> 1;          // staging: W row 0..127
    const int sg = (tid & 1) * 8;     // staging: f4 col base 0/8
    const float4* W4 = (const float4*)W;   // row = 64 f4

    if (tid == 0) sFlag = 0;
    __syncthreads();

    // stage x window once: l = 4*s0 + t, t in [0,768)
    bool nz = false;
    #pragma unroll
    for (int h = 0; h < 3; ++h) {
        int t = tid + 256 * h;
        int l = 4 * s0 + t;
        float v = (l < LL) ? in0[b * LL + l] : 0.f;
        sX[t] = v;
        nz |= (v != 0.f);
    }
    if (MODE == 1) { if (nz) atomicOr(&sFlag, 1); }
    __syncthreads();

    float acc[8][8];
    #pragma unroll
    for (int i = 0; i < 8; ++i)
        #pragma unroll
        for (int j = 0; j < 8; ++j) acc[i][j] = 0.f;

    const bool doit = (MODE == 0) || (sFlag != 0);   // block-uniform

    if (doit) {
        // stage W chunk 0: rows [0,128), k [0,64)
        {
            float4* dst = (float4*)sW[0];
            #pragma unroll
            for (int w = 0; w < 8; ++w)
                dst[sc * 17 + sg + w] = W4[sc * 64 + sg + w];
        }
        __syncthreads();

        for (int kc = 0; kc < 4; ++kc) {         // k chunks ascending
            float4 pre[8];
            if (kc < 3) {
                #pragma unroll
                for (int w = 0; w < 8; ++w)
                    pre[w] = W4[sc * 64 + (kc + 1) * 16 + sg + w];
            }

            const float* wbuf = sW[kc & 1];
            const int xoff = 64 * kc;

            for (int kk4 = 0; kk4 < 16; ++kk4) {          // k ascending
                float4 xq[8];
                #pragma unroll
                for (int j = 0; j < 8; ++j)
                    xq[j] = *(const float4*)&sX[4 * (tx + 16 * j) + xoff + 4 * kk4];
                float4 w4[8];
                #pragma unroll
                for (int i = 0; i < 8; ++i)
                    w4[i] = *(const float4*)&wbuf[(ty + 16 * i) * 68 + 4 * kk4];
                #pragma unroll
                for (int dk = 0; dk < 4; ++dk) {
                    #pragma unroll
                    for (int i = 0; i < 8; ++i) {
                        float wv = (&w4[i].x)[dk];
                        #pragma unroll
                        for (int j = 0; j < 8; ++j)
                            acc[i][j] = fmaf(wv, (&xq[j].x)[dk], acc[i][j]);
                    }
                }
            }

            if (kc < 3) {
                float4* dst = (float4*)sW[(kc + 1) & 1];
                #pragma unroll
                for (int w = 0; w < 8; ++w)
                    dst[sc * 17 + sg + w] = pre[w];
            }
            __syncthreads();
        }
    }

    // epilogue: locked fp32 elementwise chain; s-contiguous (coalesced) stores
    #pragma unroll
    for (int j = 0; j < 8; ++j) {
        int s = s0 + tx + 16 * j;
        if (s < SS) {
            #pragma unroll
            for (int i = 0; i < 8; ++i) {
                int c = ty + 16 * i;
                size_t idx = (size_t)(b * CC + c) * SS + s;
                if (MODE == 0) {
                    float d = acc[i][j];
                    drive[idx] = d;
                    u[idx] = __fmul_rn(STEP, d);   // u1 = 0 + 0.1f*drive
                } else {
                    float uo = u[idx];
                    float dr = drive[idx];
                    float a  = (fabsf(uo) > THRS) ? uo : 0.f;
                    float t1 = __fsub_rn(dr, uo);
                    float t2 = __fsub_rn(t1, acc[i][j]);
                    float t3 = __fadd_rn(t2, a);
                    float t4 = __fmul_rn(STEP, t3);
                    u[idx] = __fadd_rn(uo, t4);
                }
            }
        }
    }
}

// ---------------------------------------------------------------------------
// Transpose-conv (recon). Per-output fmaf chain IDENTICAL to rounds 5-11:
//   recon[b][4m+r]: for c = 0..127 asc, q = 0..63 asc (j = 63-q desc):
//       acc_r = fmaf(a[b][c][m-63+q], W[c][4*(63-q)+r], acc_r)
// R12 w-path: W row scalars loaded into SGPRs via inline s_load_dwordx16
// (wave-uniform -> scalar cache), consumed directly as the SGPR operand of
// v_fma_f32. Removes all v_readlane (R11 showed rdl ~8cyc + SGPR hazards).
// s_waitcnt lgkmcnt(0) INSIDE each asm block: no outstanding SMEM may cross
// an asm boundary or the compiler's own lgkmcnt bookkeeping breaks.
// ---------------------------------------------------------------------------
__global__ __launch_bounds__(256, 2) void k_recon(
    const float* __restrict__ u,
    const float* __restrict__ W,       // [C][K] natural layout
    float* __restrict__ recon)         // [B][LL]
{
    __shared__ __align__(16) float sA[32 * 320];   // 40.96 KB (stride 320)
    __shared__ int sFlag;

    const int tid = threadIdx.x;      // = m_local in [0,256)
    const int m0 = blockIdx.x * 256;
    const int b  = blockIdx.y;
    const int m  = m0 + tid;

    if (tid == 0) sFlag = 0;
    __syncthreads();

    float acc0 = 0.f, acc1 = 0.f, acc2 = 0.f, acc3 = 0.f;

    for (int cs = 0; cs < 4; ++cs) {            // 32-channel stages, c ascending
        const int c0 = cs * 32;
        // stage a = hardshrink(u): rows cl in [0,32), cols [0,319) -> m' = m0-63+col
        bool nz = false;
        for (int cl = 0; cl < 32; ++cl) {
            const float* urow = u + (size_t)(b * CC + c0 + cl) * SS + (m0 - 63);
            #pragma unroll
            for (int h = 0; h < 2; ++h) {
                int col = tid + 256 * h;
                if (col < 319) {
                    int mm = m0 - 63 + col;
                    float v = 0.f;
                    if (mm >= 0 && mm < SS) {
                        float uu = urow[col];
                        v = (fabsf(uu) > THRS) ? uu : 0.f;
                    }
                    sA[cl * 320 + col] = v;
                    nz |= (v != 0.f);
                }
            }
        }
        if (nz) atomicOr(&sFlag, 1);
        __syncthreads();                        // staging + flags complete
        const int f = sFlag;                    // block-uniform read
        __syncthreads();                        // all threads have read f
        if (tid == 0) sFlag = 0;                // reset (ordered by loop-end barrier)

        if (f) {
            for (int cl = 0; cl < 32; ++cl) {   // c ascending
                const float* arow = sA + cl * 320 + tid;     // arow[q] = a[c][m-63+q]
                const float* rowp = W + (size_t)(c0 + cl) * KK;
                #pragma unroll
                for (int g = 0; g < 8; ++g) {
                    // chunk g covers q = 8g..8g+7; floats [224-32g, 256-32g)
                    // of this W row. Hoist the 8 a-reads so ds and SMEM
                    // latencies drain together at the asm's waitcnt.
                    float av[8];
                    #pragma unroll
                    for (int t = 0; t < 8; ++t) av[t] = arow[8 * g + t];

                    v16i wA, wB;
                    asm volatile(
                        "s_load_dwordx16 %0, %2, 0\n\t"
                        "s_load_dwordx16 %1, %2, 64\n\t"
                        "s_waitcnt lgkmcnt(0)"
                        : "=s"(wA), "=s"(wB)
                        : "s"(rowp + (224 - 32 * g)));

                    #pragma unroll
                    for (int t = 0; t < 8; ++t) {   // q = 8g+t, j = 63-q desc
                        float v = av[t];
                        const int rel = 28 - 4 * t;  // 28,24,20,16,12,8,4,0
                        float wx, wy, wz, ww;
                        if (rel >= 16) {
                            wx = __int_as_float(wB[rel - 16]);
                            wy = __int_as_float(wB[rel - 15]);
                            wz = __int_as_float(wB[rel - 14]);
                            ww = __int_as_float(wB[rel - 13]);
                        } else {
                            wx = __int_as_float(wA[rel]);
                            wy = __int_as_float(wA[rel + 1]);
                            wz = __int_as_float(wA[rel + 2]);
                            ww = __int_as_float(wA[rel + 3]);
                        }
                        acc0 = fmaf(v, wx, acc0);
                        acc1 = fmaf(v, wy, acc1);
                        acc2 = fmaf(v, wz, acc2);
                        acc3 = fmaf(v, ww, acc3);
                    }
                }
            }
        }
        __syncthreads();   // sA reads done + sFlag reset visible before next stage
    }

    if (m < MM) {
        float4* o = (float4*)(recon + (size_t)b * LL + 4 * m);
        *o = make_float4(acc0, acc1, acc2, acc3);
    }
}

// ---------------------------------------------------------------------------
// Final: a = hardshrink(u) in place on d_out. 8062976 = 7874*256*4 exactly.
// ---------------------------------------------------------------------------
__global__ void k_out(float4* __restrict__ u4) {
    int idx = blockIdx.x * 256 + threadIdx.x;
    float4 v = u4[idx];
    v.x = (fabsf(v.x) > THRS) ? v.x : 0.f;
    v.y = (fabsf(v.y) > THRS) ? v.y : 0.f;
    v.z = (fabsf(v.z) > THRS) ? v.z : 0.f;
    v.w = (fabsf(v.w) > THRS) ? v.w : 0.f;
    u4[idx] = v;
}

extern "C" void kernel_launch(void* const* d_in, const int* in_sizes, int n_in,
                              void* d_out, int out_size, void* d_ws, size_t ws_size,
                              hipStream_t stream) {
    const float* x = (const float*)d_in[0];   // [16][1][16000]
    const float* W = (const float*)d_in[1];   // [128][1][256]
    float* u = (float*)d_out;                 // u lives in d_out (fp32)

    float* ws    = (float*)d_ws;              // ~33.3 MB used
    float* drive = ws;                                   // 8062976
    float* recon = drive + (size_t)BB * CC * SS;         // 256000

    dim3 gConv(31, 16);   // ceil(3937/128) x B
    k_conv<0><<<gConv, 256, 0, stream>>>(x, W, drive, u);   // drive + u1

    for (int it = 0; it < 9; ++it) {   // iterations 2..10
        k_recon<<<dim3(16, 16), 256, 0, stream>>>(u, W, recon);
        k_conv<1><<<gConv, 256, 0, stream>>>(recon, W, drive, u);
    }

    k_out<<<7874, 256, 0, stream>>>((float4*)u);
}

// Round 13
// 3438.487 us; speedup vs baseline: 1.0591x; 1.0591x over previous
//
#include <hip/hip_runtime.h>
#include <math.h>

#define BB 16
#define CC 128
#define LL 16000
#define KK 256
#define SS 3937
#define MM 4000
#define THRS 0.5f
#define STEP 0.1f   // float32(0.01/0.1) == 0.1f
#define PSTR 4096   // a_pad row stride (floats); data at [64, 64+SS)

typedef int v16i __attribute__((ext_vector_type(16)));

// ---------------------------------------------------------------------------
// Zero the whole a_pad buffer (pads must be 0; harness poisons ws each call).
// 8388608 floats = 2097152 float4 = 8192 blocks x 256.
// ---------------------------------------------------------------------------
__global__ void k_zero(float4* __restrict__ p) {
    p[blockIdx.x * 256 + threadIdx.x] = make_float4(0.f, 0.f, 0.f, 0.f);
}

// ---------------------------------------------------------------------------
// Strided conv1d (K=256, stride=4), fp32 register-tiled implicit GEMM.
// Single fmaf chain per output, k ascending 0..255. [bit-path frozen]
// R12 layout (verified): tx=s (coalesced epilogue), ty=c, W natural rows in
// LDS stride 68. MODE 0: drive/u/a_pad from x. MODE 1: LCA update + a_pad.
// MODE 2 (final): LCA update, store hardshrink(u_new) directly to u (=d_out).
// ---------------------------------------------------------------------------
template<int MODE>
__global__ __launch_bounds__(256, 2) void k_conv(
    const float* __restrict__ in0,     // x (MODE 0) or recon (MODE 1/2)
    const float* __restrict__ W,       // [C][K] natural
    float* __restrict__ drive,
    float* __restrict__ u,
    float* __restrict__ apad)          // [B*C][PSTR], data at +64
{
    __shared__ __align__(16) float sW[2][128 * 68];  // 2 x 34.8 KB
    __shared__ __align__(16) float sX[768];
    __shared__ int sFlag;

    const int tid = threadIdx.x;
    const int tx = tid & 15;          // s-minor
    const int ty = tid >> 4;          // c-minor
    const int s0 = blockIdx.x * 128;
    const int b  = blockIdx.y;

    const int sc = tid >> 1;
    const int sg = (tid & 1) * 8;
    const float4* W4 = (const float4*)W;

    if (tid == 0) sFlag = 0;
    __syncthreads();

    bool nz = false;
    #pragma unroll
    for (int h = 0; h < 3; ++h) {
        int t = tid + 256 * h;
        int l = 4 * s0 + t;
        float v = (l < LL) ? in0[b * LL + l] : 0.f;
        sX[t] = v;
        nz |= (v != 0.f);
    }
    if (MODE != 0) { if (nz) atomicOr(&sFlag, 1); }
    __syncthreads();

    float acc[8][8];
    #pragma unroll
    for (int i = 0; i < 8; ++i)
        #pragma unroll
        for (int j = 0; j < 8; ++j) acc[i][j] = 0.f;

    const bool doit = (MODE == 0) || (sFlag != 0);   // block-uniform

    if (doit) {
        {
            float4* dst = (float4*)sW[0];
            #pragma unroll
            for (int w = 0; w < 8; ++w)
                dst[sc * 17 + sg + w] = W4[sc * 64 + sg + w];
        }
        __syncthreads();

        for (int kc = 0; kc < 4; ++kc) {         // k chunks ascending
            float4 pre[8];
            if (kc < 3) {
                #pragma unroll
                for (int w = 0; w < 8; ++w)
                    pre[w] = W4[sc * 64 + (kc + 1) * 16 + sg + w];
            }

            const float* wbuf = sW[kc & 1];
            const int xoff = 64 * kc;

            for (int kk4 = 0; kk4 < 16; ++kk4) {          // k ascending
                float4 xq[8];
                #pragma unroll
                for (int j = 0; j < 8; ++j)
                    xq[j] = *(const float4*)&sX[4 * (tx + 16 * j) + xoff + 4 * kk4];
                float4 w4[8];
                #pragma unroll
                for (int i = 0; i < 8; ++i)
                    w4[i] = *(const float4*)&wbuf[(ty + 16 * i) * 68 + 4 * kk4];
                #pragma unroll
                for (int dk = 0; dk < 4; ++dk) {
                    #pragma unroll
                    for (int i = 0; i < 8; ++i) {
                        float wv = (&w4[i].x)[dk];
                        #pragma unroll
                        for (int j = 0; j < 8; ++j)
                            acc[i][j] = fmaf(wv, (&xq[j].x)[dk], acc[i][j]);
                    }
                }
            }

            if (kc < 3) {
                float4* dst = (float4*)sW[(kc + 1) & 1];
                #pragma unroll
                for (int w = 0; w < 8; ++w)
                    dst[sc * 17 + sg + w] = pre[w];
            }
            __syncthreads();
        }
    }

    // epilogue: locked fp32 elementwise chain; s-contiguous stores
    #pragma unroll
    for (int j = 0; j < 8; ++j) {
        int s = s0 + tx + 16 * j;
        if (s < SS) {
            #pragma unroll
            for (int i = 0; i < 8; ++i) {
                int c = ty + 16 * i;
                size_t idx  = (size_t)(b * CC + c) * SS + s;
                size_t pidx = ((size_t)(b * CC + c) << 12) + 64 + s;
                if (MODE == 0) {
                    float d = acc[i][j];
                    drive[idx] = d;
                    float un = __fmul_rn(STEP, d);   // u1 = 0 + 0.1f*drive
                    u[idx] = un;
                    apad[pidx] = (fabsf(un) > THRS) ? un : 0.f;
                } else {
                    float uo = u[idx];
                    float dr = drive[idx];
                    float a  = (fabsf(uo) > THRS) ? uo : 0.f;
                    float t1 = __fsub_rn(dr, uo);
                    float t2 = __fsub_rn(t1, acc[i][j]);
                    float t3 = __fadd_rn(t2, a);
                    float t4 = __fmul_rn(STEP, t3);
                    float un = __fadd_rn(uo, t4);
                    if (MODE == 1) {
                        u[idx] = un;
                        apad[pidx] = (fabsf(un) > THRS) ? un : 0.f;
                    } else {   // MODE 2: final — d_out gets a = hardshrink(u10)
                        u[idx] = (fabsf(un) > THRS) ? un : 0.f;
                    }
                }
            }
        }
    }
}

// ---------------------------------------------------------------------------
// Transpose-conv (recon). Per-output fmaf chain IDENTICAL to rounds 5-12:
//   recon[b][4m+r]: for c = 0..127 asc, q = 0..63 asc (j = 63-q desc):
//       acc_r = fmaf(a[b][c][m-63+q], W[c][4*(63-q)+r], acc_r)
// R13: NO LDS at all. a read straight from zero-padded a_pad (coalesced
// per-lane b32, L1-hot, pipelined on vmcnt). W in SGPRs via R12's verified
// s_load_dwordx16 chunks — lgkmcnt now carries ONLY SMEM, so the blocking
// wait no longer nukes a ds pipeline (R12's failure mode).
// ---------------------------------------------------------------------------
__global__ __launch_bounds__(256, 2) void k_recon(
    const float* __restrict__ apad,    // [B*C][PSTR], data at +64
    const float* __restrict__ W,       // [C][K]
    float* __restrict__ recon)         // [B][LL]
{
    const int tid = threadIdx.x;
    const int m0 = blockIdx.x * 256;
    const int b  = blockIdx.y;
    const int m  = m0 + tid;
    const int mc = (m < MM) ? m : (MM - 1);   // clamp address for tail threads

    float acc0 = 0.f, acc1 = 0.f, acc2 = 0.f, acc3 = 0.f;

    for (int c = 0; c < CC; ++c) {            // c ascending [bit-order]
        // arow[q] = a[b][c][m-63+q]  (pad offset 64: idx = 64 + m-63+q = 1+m+q)
        const float* arow = apad + (((size_t)(b * CC + c)) << 12) + 1 + mc;
        const float* rowp = W + (size_t)c * KK;
        #pragma unroll
        for (int g = 0; g < 8; ++g) {         // q = 8g..8g+7
            float av[8];
            #pragma unroll
            for (int t = 0; t < 8; ++t) av[t] = arow[8 * g + t];   // vmcnt path

            v16i wA, wB;
            asm volatile(
                "s_load_dwordx16 %0, %2, 0\n\t"
                "s_load_dwordx16 %1, %2, 64\n\t"
                "s_waitcnt lgkmcnt(0)"
                : "=s"(wA), "=s"(wB)
                : "s"(rowp + (224 - 32 * g)));

            #pragma unroll
            for (int t = 0; t < 8; ++t) {     // q = 8g+t, j = 63-q desc
                float v = av[t];
                const int rel = 28 - 4 * t;   // 28,24,20,16,12,8,4,0
                float wx, wy, wz, ww;
                if (rel >= 16) {
                    wx = __int_as_float(wB[rel - 16]);
                    wy = __int_as_float(wB[rel - 15]);
                    wz = __int_as_float(wB[rel - 14]);
                    ww = __int_as_float(wB[rel - 13]);
                } else {
                    wx = __int_as_float(wA[rel]);
                    wy = __int_as_float(wA[rel + 1]);
                    wz = __int_as_float(wA[rel + 2]);
                    ww = __int_as_float(wA[rel + 3]);
                }
                acc0 = fmaf(v, wx, acc0);
                acc1 = fmaf(v, wy, acc1);
                acc2 = fmaf(v, wz, acc2);
                acc3 = fmaf(v, ww, acc3);
            }
        }
    }

    if (m < MM) {
        float4* o = (float4*)(recon + (size_t)b * LL + 4 * m);
        *o = make_float4(acc0, acc1, acc2, acc3);
    }
}

extern "C" void kernel_launch(void* const* d_in, const int* in_sizes, int n_in,
                              void* d_out, int out_size, void* d_ws, size_t ws_size,
                              hipStream_t stream) {
    const float* x = (const float*)d_in[0];   // [16][1][16000]
    const float* W = (const float*)d_in[1];   // [128][1][256]
    float* u = (float*)d_out;                 // u lives in d_out (fp32)

    float* ws    = (float*)d_ws;              // ~67 MB used
    float* drive = ws;                                    // 8062976
    float* recon = drive + (size_t)BB * CC * SS;          // 256000
    float* apad  = recon + (size_t)BB * LL;               // 2048*4096 = 8388608

    k_zero<<<8192, 256, 0, stream>>>((float4*)apad);      // pads must be 0

    dim3 gConv(31, 16);   // ceil(3937/128) x B
    k_conv<0><<<gConv, 256, 0, stream>>>(x, W, drive, u, apad);   // drive+u1+a1

    for (int it = 0; it < 9; ++it) {   // iterations 2..10
        k_recon<<<dim3(16, 16), 256, 0, stream>>>(apad, W, recon);
        if (it < 8)
            k_conv<1><<<gConv, 256, 0, stream>>>(recon, W, drive, u, apad);
        else
            k_conv<2><<<gConv, 256, 0, stream>>>(recon, W, drive, u, apad);
    }
}

// Round 14
// 2410.309 us; speedup vs baseline: 1.5109x; 1.4266x over previous
//
#include <hip/hip_runtime.h>
#include <math.h>

#define BB 16
#define CC 128
#define LL 16000
#define KK 256
#define SS 3937
#define MM 4000
#define THRS 0.5f
#define STEP 0.1f   // float32(0.01/0.1) == 0.1f

// ---------------------------------------------------------------------------
// Strided conv1d (K=256, stride=4), fp32 register-tiled implicit GEMM.
// Single fmaf chain per output, k ascending 0..255. [bit-path frozen]
// R12 layout (proven ~56us): tx=s (coalesced epilogue), ty=c, W natural rows
// in LDS stride 68 (broadcast + conflict-free). Double-buffered W chunks.
// MODE 0: drive = conv, u = 0.1f*conv (iter-1 analytic).
// MODE 1: locked-fp32 LCA update of u.
// MODE 2: final iteration — write hardshrink(u_new) directly to u (=d_out).
// ---------------------------------------------------------------------------
template<int MODE>
__global__ __launch_bounds__(256, 2) void k_conv(
    const float* __restrict__ in0,     // x (MODE 0) or recon (MODE 1/2)
    const float* __restrict__ W,       // [C][K] natural
    float* __restrict__ drive,
    float* __restrict__ u)
{
    __shared__ __align__(16) float sW[2][128 * 68];  // 2 x 34.8 KB
    __shared__ __align__(16) float sX[768];
    __shared__ int sFlag;

    const int tid = threadIdx.x;
    const int tx = tid & 15;          // s-minor
    const int ty = tid >> 4;          // c-minor
    const int s0 = blockIdx.x * 128;
    const int b  = blockIdx.y;

    const int sc = tid >> 1;
    const int sg = (tid & 1) * 8;
    const float4* W4 = (const float4*)W;

    if (tid == 0) sFlag = 0;
    __syncthreads();

    bool nz = false;
    #pragma unroll
    for (int h = 0; h < 3; ++h) {
        int t = tid + 256 * h;
        int l = 4 * s0 + t;
        float v = (l < LL) ? in0[b * LL + l] : 0.f;
        sX[t] = v;
        nz |= (v != 0.f);
    }
    if (MODE != 0) { if (nz) atomicOr(&sFlag, 1); }
    __syncthreads();

    float acc[8][8];
    #pragma unroll
    for (int i = 0; i < 8; ++i)
        #pragma unroll
        for (int j = 0; j < 8; ++j) acc[i][j] = 0.f;

    const bool doit = (MODE == 0) || (sFlag != 0);   // block-uniform

    if (doit) {
        {
            float4* dst = (float4*)sW[0];
            #pragma unroll
            for (int w = 0; w < 8; ++w)
                dst[sc * 17 + sg + w] = W4[sc * 64 + sg + w];
        }
        __syncthreads();

        for (int kc = 0; kc < 4; ++kc) {         // k chunks ascending
            float4 pre[8];
            if (kc < 3) {
                #pragma unroll
                for (int w = 0; w < 8; ++w)
                    pre[w] = W4[sc * 64 + (kc + 1) * 16 + sg + w];
            }

            const float* wbuf = sW[kc & 1];
            const int xoff = 64 * kc;

            for (int kk4 = 0; kk4 < 16; ++kk4) {          // k ascending
                float4 xq[8];
                #pragma unroll
                for (int j = 0; j < 8; ++j)
                    xq[j] = *(const float4*)&sX[4 * (tx + 16 * j) + xoff + 4 * kk4];
                float4 w4[8];
                #pragma unroll
                for (int i = 0; i < 8; ++i)
                    w4[i] = *(const float4*)&wbuf[(ty + 16 * i) * 68 + 4 * kk4];
                #pragma unroll
                for (int dk = 0; dk < 4; ++dk) {
                    #pragma unroll
                    for (int i = 0; i < 8; ++i) {
                        float wv = (&w4[i].x)[dk];
                        #pragma unroll
                        for (int j = 0; j < 8; ++j)
                            acc[i][j] = fmaf(wv, (&xq[j].x)[dk], acc[i][j]);
                    }
                }
            }

            if (kc < 3) {
                float4* dst = (float4*)sW[(kc + 1) & 1];
                #pragma unroll
                for (int w = 0; w < 8; ++w)
                    dst[sc * 17 + sg + w] = pre[w];
            }
            __syncthreads();
        }
    }

    // epilogue: locked fp32 elementwise chain; s-contiguous stores
    #pragma unroll
    for (int j = 0; j < 8; ++j) {
        int s = s0 + tx + 16 * j;
        if (s < SS) {
            #pragma unroll
            for (int i = 0; i < 8; ++i) {
                int c = ty + 16 * i;
                size_t idx = (size_t)(b * CC + c) * SS + s;
                if (MODE == 0) {
                    float d = acc[i][j];
                    drive[idx] = d;
                    u[idx] = __fmul_rn(STEP, d);   // u1 = 0 + 0.1f*drive
                } else {
                    float uo = u[idx];
                    float dr = drive[idx];
                    float a  = (fabsf(uo) > THRS) ? uo : 0.f;
                    float t1 = __fsub_rn(dr, uo);
                    float t2 = __fsub_rn(t1, acc[i][j]);
                    float t3 = __fadd_rn(t2, a);
                    float t4 = __fmul_rn(STEP, t3);
                    float un = __fadd_rn(uo, t4);
                    if (MODE == 1) u[idx] = un;
                    else           u[idx] = (fabsf(un) > THRS) ? un : 0.f;  // final
                }
            }
        }
    }
}

// ---------------------------------------------------------------------------
// float readlane via int builtin (lane is compile-time constant here)
// ---------------------------------------------------------------------------
__device__ __forceinline__ float rdlane_f(float v, int lane) {
    union { float f; int i; } u;
    u.f = v;
    u.i = __builtin_amdgcn_readlane(u.i, lane);
    return u.f;
}

// ---------------------------------------------------------------------------
// Transpose-conv (recon) — ROUND-9 KERNEL VERBATIM (best measured: 196 us).
// Per-output fmaf chain [bit-path frozen]:
//   recon[b][4m+r]: for c = 0..127 asc, q = 0..63 asc (j = 63-q desc):
//       acc_r = fmaf(a[b][c][m-63+q], W[c][4*(63-q)+r], acc_r)
// w-path: one coalesced b128 per wave per cl + v_readlane broadcast.
// a-path: LDS b32 per q (compiler pairs into ds_read2_b32).
// R8/R12/R13 lessons: no uniform global loads in-loop, no s_load waits.
// ---------------------------------------------------------------------------
__global__ __launch_bounds__(256, 2) void k_recon(
    const float* __restrict__ u,
    const float* __restrict__ W,       // [C][K] natural layout
    float* __restrict__ recon)         // [B][LL]
{
    __shared__ __align__(16) float sA[32 * 320];   // 40.96 KB (stride 320)
    __shared__ int sFlag;

    const int tid = threadIdx.x;      // = m_local in [0,256)
    const int lane = tid & 63;
    const int m0 = blockIdx.x * 256;
    const int b  = blockIdx.y;
    const int m  = m0 + tid;

    if (tid == 0) sFlag = 0;
    __syncthreads();

    float acc0 = 0.f, acc1 = 0.f, acc2 = 0.f, acc3 = 0.f;

    for (int cs = 0; cs < 4; ++cs) {            // 32-channel stages, c ascending
        const int c0 = cs * 32;
        bool nz = false;
        for (int cl = 0; cl < 32; ++cl) {
            const float* urow = u + (size_t)(b * CC + c0 + cl) * SS + (m0 - 63);
            #pragma unroll
            for (int h = 0; h < 2; ++h) {
                int col = tid + 256 * h;
                if (col < 319) {
                    int mm = m0 - 63 + col;
                    float v = 0.f;
                    if (mm >= 0 && mm < SS) {
                        float uu = urow[col];
                        v = (fabsf(uu) > THRS) ? uu : 0.f;
                    }
                    sA[cl * 320 + col] = v;
                    nz |= (v != 0.f);
                }
            }
        }
        if (nz) atomicOr(&sFlag, 1);
        __syncthreads();                        // staging + flags complete
        const int f = sFlag;                    // block-uniform read
        __syncthreads();                        // all threads have read f
        if (tid == 0) sFlag = 0;                // reset (ordered by loop-end barrier)

        if (f) {
            for (int cl = 0; cl < 32; ++cl) {   // c ascending
                const float* arow = sA + cl * 320 + tid;     // arow[q] = a[c][m-63+q]
                float4 wv = ((const float4*)(W + (size_t)(c0 + cl) * KK))[lane];
                #pragma unroll
                for (int q = 0; q < 64; ++q) {  // j = 63-q descending
                    float v  = arow[q];
                    float wx = rdlane_f(wv.x, 63 - q);
                    float wy = rdlane_f(wv.y, 63 - q);
                    float wz = rdlane_f(wv.z, 63 - q);
                    float ww = rdlane_f(wv.w, 63 - q);
                    acc0 = fmaf(v, wx, acc0);
                    acc1 = fmaf(v, wy, acc1);
                    acc2 = fmaf(v, wz, acc2);
                    acc3 = fmaf(v, ww, acc3);
                }
            }
        }
        __syncthreads();   // sA reads done + sFlag reset visible before next stage
    }

    if (m < MM) {
        float4* o = (float4*)(recon + (size_t)b * LL + 4 * m);
        *o = make_float4(acc0, acc1, acc2, acc3);
    }
}

extern "C" void kernel_launch(void* const* d_in, const int* in_sizes, int n_in,
                              void* d_out, int out_size, void* d_ws, size_t ws_size,
                              hipStream_t stream) {
    const float* x = (const float*)d_in[0];   // [16][1][16000]
    const float* W = (const float*)d_in[1];   // [128][1][256]
    float* u = (float*)d_out;                 // u lives in d_out (fp32)

    float* ws    = (float*)d_ws;              // ~33.3 MB used
    float* drive = ws;                                    // 8062976
    float* recon = drive + (size_t)BB * CC * SS;          // 256000

    dim3 gConv(31, 16);   // ceil(3937/128) x B
    k_conv<0><<<gConv, 256, 0, stream>>>(x, W, drive, u);   // drive + u1

    for (int it = 0; it < 9; ++it) {   // iterations 2..10
        k_recon<<<dim3(16, 16), 256, 0, stream>>>(u, W, recon);
        if (it < 8)
            k_conv<1><<<gConv, 256, 0, stream>>>(recon, W, drive, u);
        else
            k_conv<2><<<gConv, 256, 0, stream>>>(recon, W, drive, u);  // final -> d_out
    }
}